// Round 1
// baseline (69.700 us; speedup 1.0000x reference)
//
#include <hip/hip_runtime.h>
#include <math.h>

// B=64, C=3, H=W=256 fixed by the reference problem.
#define BATCH 64
#define CH 3
#define IMH 256
#define IMW 256

// --- Setup kernel: compute per-batch inverse affine coefficients ---
// Writes 8 floats per batch into ws: ia, ib, ic, id, ie, if_, pad, pad
__global__ void TCR_52536039964687_coef(const float* __restrict__ rnd,
                                        float* __restrict__ coef) {
    int b = threadIdx.x;
    if (b >= BATCH) return;
    const float r = rnd[b];

    // ANG = deg2rad(20), MAX_T = 6
    const float ANG  = 0.34906585039886590f;
    const float ANG2 = 0.69813170079773179f; // 2*ANG

    float tx  = 12.0f * r - 6.0f;   // 2*MAX_T*r - MAX_T
    float ty  = tx;
    float rot = ANG2 * r - ANG;
    float hx  = rot, hy = rot;
    float aa  = hx - rot;           // == 0, keep general form
    float bb  = hy + rot;

    float chx = cosf(hx), chy = cosf(hy);
    float ca = cosf(aa), sa = sinf(aa);
    float cb = cosf(bb), sb = sinf(bb);

    const float Wc = (float)IMH;   // reference: Wc = img.shape[2]
    const float Hc = (float)IMW;   // reference: Hc = img.shape[3]

    float T11 = ca / chx;
    float T12 = sa / chx;
    float T13 = (Wc * chx - Wc * ca + 2.f * tx * ca - Hc * sa + 2.f * ty * sa) / (2.f * chx);
    float T21 = sb / chy;
    float T22 = cb / chy;
    float T23 = (Hc * chy - Wc * cb + 2.f * ty * cb - Wc * sb + 2.f * tx * sb) / (2.f * chy);

    float det = T11 * T22 - T12 * T21;
    float ia  = T22 / det;
    float ib  = -T12 / det;
    float id_ = -T21 / det;
    float ie  = T11 / det;
    float ic  = -(ia * T13 + ib * T23);
    float if_ = -(id_ * T13 + ie * T23);

    float* o = coef + b * 8;
    o[0] = ia; o[1] = ib; o[2] = ic;
    o[3] = id_; o[4] = ie; o[5] = if_;
}

// --- Main warp kernel: one thread per (b, y, x), loops over 3 channels ---
__global__ __launch_bounds__(256) void TCR_52536039964687_warp(
    const float* __restrict__ img,
    const float* __restrict__ coef,
    float* __restrict__ out) {
    // blockIdx.x in [0, BATCH*IMH): b*IMH + y ; threadIdx.x = x
    int bid = blockIdx.x;
    int b = bid >> 8;       // / IMH
    int y = bid & 255;      // % IMH
    int x = threadIdx.x;

    const float* cf = coef + b * 8;   // b is block-uniform -> scalar loads
    float ia = cf[0], ib = cf[1], ic = cf[2];
    float id_ = cf[3], ie = cf[4], if_ = cf[5];

    float fx = (float)x, fy = (float)y;
    float sx = ia * fx + ib * fy + ic;
    float sy = id_ * fx + ie * fy + if_;

    float x0f = floorf(sx), y0f = floorf(sy);
    int x0 = (int)x0f, y0 = (int)y0f;
    int x1 = x0 + 1, y1 = y0 + 1;
    float wx = sx - x0f, wy = sy - y0f;

    float w00 = (1.f - wx) * (1.f - wy);
    float w01 = wx * (1.f - wy);
    float w10 = (1.f - wx) * wy;
    float w11 = wx * wy;

    bool vx0 = (x0 >= 0) & (x0 < IMW);
    bool vx1 = (x1 >= 0) & (x1 < IMW);
    bool vy0 = (y0 >= 0) & (y0 < IMH);
    bool vy1 = (y1 >= 0) & (y1 < IMH);

    // fold validity into weights (v * valid * w == v * (valid ? w : 0))
    float m00 = (vy0 && vx0) ? w00 : 0.f;
    float m01 = (vy0 && vx1) ? w01 : 0.f;
    float m10 = (vy1 && vx0) ? w10 : 0.f;
    float m11 = (vy1 && vx1) ? w11 : 0.f;

    int cx0 = min(max(x0, 0), IMW - 1);
    int cx1 = min(max(x1, 0), IMW - 1);
    int cy0 = min(max(y0, 0), IMH - 1);
    int cy1 = min(max(y1, 0), IMH - 1);

    int i00 = cy0 * IMW + cx0;
    int i01 = cy0 * IMW + cx1;
    int i10 = cy1 * IMW + cx0;
    int i11 = cy1 * IMW + cx1;

    const float* base = img + (size_t)b * CH * (IMH * IMW);
    float* obase = out + (size_t)b * CH * (IMH * IMW) + y * IMW + x;

    #pragma unroll
    for (int c = 0; c < CH; ++c) {
        const float* p = base + c * (IMH * IMW);
        float v = p[i00] * m00 + p[i01] * m01 + p[i10] * m10 + p[i11] * m11;
        obase[c * (IMH * IMW)] = v;
    }
}

extern "C" void kernel_launch(void* const* d_in, const int* in_sizes, int n_in,
                              void* d_out, int out_size, void* d_ws, size_t ws_size,
                              hipStream_t stream) {
    const float* img = (const float*)d_in[0];
    const float* rnd = (const float*)d_in[1];
    float* out = (float*)d_out;
    float* coef = (float*)d_ws;   // 64 * 8 floats = 2 KB scratch

    hipLaunchKernelGGL(TCR_52536039964687_coef, dim3(1), dim3(64), 0, stream, rnd, coef);
    hipLaunchKernelGGL(TCR_52536039964687_warp, dim3(BATCH * IMH), dim3(256), 0, stream,
                       img, coef, out);
}

// Round 2
// 52.785 us; speedup vs baseline: 1.3205x; 1.3205x over previous
//
#include <hip/hip_runtime.h>
#include <math.h>

// B=64, C=3, H=W=256 fixed by the reference problem.
#define BATCH 64
#define CH 3
#define IMH 256
#define IMW 256
#define NXCD 8

// --- Setup kernel: compute per-batch inverse affine coefficients ---
// Writes 8 floats per batch into ws: ia, ib, ic, id, ie, if_, pad, pad
__global__ void TCR_52536039964687_coef(const float* __restrict__ rnd,
                                        float* __restrict__ coef) {
    int b = threadIdx.x;
    if (b >= BATCH) return;
    const float r = rnd[b];

    // ANG = deg2rad(20), MAX_T = 6
    const float ANG  = 0.34906585039886590f;
    const float ANG2 = 0.69813170079773179f; // 2*ANG

    float tx  = 12.0f * r - 6.0f;   // 2*MAX_T*r - MAX_T
    float ty  = tx;
    float rot = ANG2 * r - ANG;
    float hx  = rot, hy = rot;
    float aa  = hx - rot;           // == 0, keep general form
    float bb  = hy + rot;

    float chx = cosf(hx), chy = cosf(hy);
    float ca = cosf(aa), sa = sinf(aa);
    float cb = cosf(bb), sb = sinf(bb);

    const float Wc = (float)IMH;   // reference: Wc = img.shape[2]
    const float Hc = (float)IMW;   // reference: Hc = img.shape[3]

    float T11 = ca / chx;
    float T12 = sa / chx;
    float T13 = (Wc * chx - Wc * ca + 2.f * tx * ca - Hc * sa + 2.f * ty * sa) / (2.f * chx);
    float T21 = sb / chy;
    float T22 = cb / chy;
    float T23 = (Hc * chy - Wc * cb + 2.f * ty * cb - Wc * sb + 2.f * tx * sb) / (2.f * chy);

    float det = T11 * T22 - T12 * T21;
    float ia  = T22 / det;
    float ib  = -T12 / det;
    float id_ = -T21 / det;
    float ie  = T11 / det;
    float ic  = -(ia * T13 + ib * T23);
    float if_ = -(id_ * T13 + ie * T23);

    float* o = coef + b * 8;
    o[0] = ia; o[1] = ib; o[2] = ic;
    o[3] = id_; o[4] = ie; o[5] = if_;
}

// --- Main warp kernel: one thread per (b, y, x), loops over 3 channels ---
// blockIdx swizzled so that all 256 rows of image b run on XCD b%8:
// assuming HW round-robin xcd = bid%8, we decode bid -> (b,y) as below.
__global__ __launch_bounds__(256) void TCR_52536039964687_warp(
    const float* __restrict__ img,
    const float* __restrict__ coef,
    float* __restrict__ out) {
    int w = blockIdx.x;             // [0, 64*256)
    int xcd = w & (NXCD - 1);       // which XCD this block lands on
    int t = w >> 3;                 // within-XCD sequence [0, 2048)
    int b = ((t >> 8) << 3) | xcd;  // image: all rows of b share XCD b%8
    int y = t & 255;                // row within image
    int x = threadIdx.x;

    const float* cf = coef + b * 8;   // b is block-uniform -> scalar loads
    float ia = cf[0], ib = cf[1], ic = cf[2];
    float id_ = cf[3], ie = cf[4], if_ = cf[5];

    float fx = (float)x, fy = (float)y;
    float sx = ia * fx + ib * fy + ic;
    float sy = id_ * fx + ie * fy + if_;

    float x0f = floorf(sx), y0f = floorf(sy);
    int x0 = (int)x0f, y0 = (int)y0f;
    int x1 = x0 + 1, y1 = y0 + 1;
    float wx = sx - x0f, wy = sy - y0f;

    float w00 = (1.f - wx) * (1.f - wy);
    float w01 = wx * (1.f - wy);
    float w10 = (1.f - wx) * wy;
    float w11 = wx * wy;

    bool vx0 = (x0 >= 0) & (x0 < IMW);
    bool vx1 = (x1 >= 0) & (x1 < IMW);
    bool vy0 = (y0 >= 0) & (y0 < IMH);
    bool vy1 = (y1 >= 0) & (y1 < IMH);

    // fold validity into weights (v * valid * w == v * (valid ? w : 0))
    float m00 = (vy0 && vx0) ? w00 : 0.f;
    float m01 = (vy0 && vx1) ? w01 : 0.f;
    float m10 = (vy1 && vx0) ? w10 : 0.f;
    float m11 = (vy1 && vx1) ? w11 : 0.f;

    int cx0 = min(max(x0, 0), IMW - 1);
    int cx1 = min(max(x1, 0), IMW - 1);
    int cy0 = min(max(y0, 0), IMH - 1);
    int cy1 = min(max(y1, 0), IMH - 1);

    int i00 = cy0 * IMW + cx0;
    int i01 = cy0 * IMW + cx1;
    int i10 = cy1 * IMW + cx0;
    int i11 = cy1 * IMW + cx1;

    const float* base = img + (size_t)b * CH * (IMH * IMW);
    float* obase = out + (size_t)b * CH * (IMH * IMW) + y * IMW + x;

    #pragma unroll
    for (int c = 0; c < CH; ++c) {
        const float* p = base + c * (IMH * IMW);
        float v = p[i00] * m00 + p[i01] * m01 + p[i10] * m10 + p[i11] * m11;
        // output is never re-read: nontemporal store keeps L2 for input
        __builtin_nontemporal_store(v, obase + c * (IMH * IMW));
    }
}

extern "C" void kernel_launch(void* const* d_in, const int* in_sizes, int n_in,
                              void* d_out, int out_size, void* d_ws, size_t ws_size,
                              hipStream_t stream) {
    const float* img = (const float*)d_in[0];
    const float* rnd = (const float*)d_in[1];
    float* out = (float*)d_out;
    float* coef = (float*)d_ws;   // 64 * 8 floats = 2 KB scratch

    hipLaunchKernelGGL(TCR_52536039964687_coef, dim3(1), dim3(64), 0, stream, rnd, coef);
    hipLaunchKernelGGL(TCR_52536039964687_warp, dim3(BATCH * IMH), dim3(256), 0, stream,
                       img, coef, out);
}

// Round 3
// 39.499 us; speedup vs baseline: 1.7646x; 1.3364x over previous
//
#include <hip/hip_runtime.h>
#include <math.h>

// B=64, C=3, H=W=256 fixed by the reference problem.
#define BATCH 64
#define CH 3
#define IMH 256
#define IMW 256
#define HW (IMH * IMW)
#define NXCD 8

// 8-byte gather of two adjacent floats; align(4) so the compiler emits
// global_load_dwordx2 with 4B alignment (gfx9+ unaligned access mode).
struct F2 { float lo, hi; };

__device__ __forceinline__ F2 load_f2(const float* p) {
    F2 v;
    __builtin_memcpy(&v, p, 8);
    return v;
}

// One thread per (b, y, x); coefficients computed in-kernel per thread
// (identical formula per image -> deterministic, ~20 VALU ops, negligible
// vs gather cost; removes the serialized setup dispatch).
__global__ __launch_bounds__(256) void TCR_52536039964687_warp(
    const float* __restrict__ img,
    const float* __restrict__ rnd,
    float* __restrict__ out) {
    // XCD-affinity swizzle: all 256 rows of image b land on XCD b%8
    // (assuming HW round-robin xcd = bid % 8; perf-only assumption).
    int w = blockIdx.x;             // [0, 64*256)
    int xcd = w & (NXCD - 1);
    int t = w >> 3;                 // within-XCD sequence [0, 2048)
    int b = ((t >> 8) << 3) | xcd;  // image index
    int y = t & 255;                // output row
    int x = threadIdx.x;            // output col

    // ---- per-image affine coefficients (inverse matrix) ----
    const float r = rnd[b];
    const float ANG  = 0.34906585039886590f;   // deg2rad(20)
    const float ANG2 = 0.69813170079773179f;   // 2*ANG

    float tx  = 12.0f * r - 6.0f;
    float ty  = tx;
    float rot = ANG2 * r - ANG;
    float hx  = rot, hy = rot;
    float aa  = hx - rot;           // == 0 analytically; keep general form
    float bb  = hy + rot;

    float chx = cosf(hx), chy = cosf(hy);
    float ca = cosf(aa), sa = sinf(aa);
    float cb = cosf(bb), sb = sinf(bb);

    const float Wc = (float)IMH;    // reference: Wc = img.shape[2]
    const float Hc = (float)IMW;    // reference: Hc = img.shape[3]

    float T11 = ca / chx;
    float T12 = sa / chx;
    float T13 = (Wc * chx - Wc * ca + 2.f * tx * ca - Hc * sa + 2.f * ty * sa) / (2.f * chx);
    float T21 = sb / chy;
    float T22 = cb / chy;
    float T23 = (Hc * chy - Wc * cb + 2.f * ty * cb - Wc * sb + 2.f * tx * sb) / (2.f * chy);

    float det = T11 * T22 - T12 * T21;
    float ia  = T22 / det;
    float ib  = -T12 / det;
    float id_ = -T21 / det;
    float ie  = T11 / det;
    float ic  = -(ia * T13 + ib * T23);
    float if_ = -(id_ * T13 + ie * T23);

    // ---- source position ----
    float fx = (float)x, fy = (float)y;
    float sx = ia * fx + ib * fy + ic;
    float sy = id_ * fx + ie * fy + if_;

    float x0f = floorf(sx), y0f = floorf(sy);
    int x0 = (int)x0f, y0 = (int)y0f;
    float wx = sx - x0f, wy = sy - y0f;

    // ---- fused x-taps: one 8B load at lx covers both x0 and x1=x0+1 ----
    // Remap lo/hi weights by where x0 sits relative to lx; invalid taps -> 0.
    int lx = min(max(x0, 0), IMW - 2);
    float wl = (x0 == lx) ? (1.f - wx) : ((x0 == lx - 1) ? wx : 0.f);
    float wh = (x0 == lx) ? wx : ((x0 == lx + 1) ? (1.f - wx) : 0.f);

    // ---- y-taps: validity folded into row weights ----
    int y1 = y0 + 1;
    float wy0 = ((y0 >= 0) & (y0 < IMH)) ? (1.f - wy) : 0.f;
    float wy1 = ((y1 >= 0) & (y1 < IMH)) ? wy : 0.f;
    int cy0 = min(max(y0, 0), IMH - 1);
    int cy1 = min(max(y1, 0), IMH - 1);

    const float* base = img + (size_t)b * CH * HW;
    const float* r0 = base + cy0 * IMW + lx;
    const float* r1 = base + cy1 * IMW + lx;
    float* ob = out + (size_t)b * CH * HW + y * IMW + x;

    #pragma unroll
    for (int c = 0; c < CH; ++c) {
        F2 a0 = load_f2(r0 + c * HW);
        F2 a1 = load_f2(r1 + c * HW);
        float v = (a0.lo * wl + a0.hi * wh) * wy0
                + (a1.lo * wl + a1.hi * wh) * wy1;
        // output is never re-read: nontemporal store keeps L2 for input
        __builtin_nontemporal_store(v, ob + c * HW);
    }
}

extern "C" void kernel_launch(void* const* d_in, const int* in_sizes, int n_in,
                              void* d_out, int out_size, void* d_ws, size_t ws_size,
                              hipStream_t stream) {
    const float* img = (const float*)d_in[0];
    const float* rnd = (const float*)d_in[1];
    float* out = (float*)d_out;
    (void)d_ws; (void)ws_size;

    hipLaunchKernelGGL(TCR_52536039964687_warp, dim3(BATCH * IMH), dim3(256), 0, stream,
                       img, rnd, out);
}

// Round 4
// 36.679 us; speedup vs baseline: 1.9003x; 1.0769x over previous
//
#include <hip/hip_runtime.h>
#include <math.h>

// B=64, C=3, H=W=256 fixed by the reference problem.
#define BATCH 64
#define CH 3
#define IMH 256
#define IMW 256
#define HW (IMH * IMW)
#define NXCD 8

struct F2 { float lo, hi; };

__device__ __forceinline__ F2 load_f2(const float* p) {
    F2 v;
    __builtin_memcpy(&v, p, 8);
    return v;
}

// One thread per (b, y, x). Coefficients computed per-thread via the
// analytically simplified inverse (a = hx - r == 0.0f exactly in the
// reference, so T12 == 0):
//   sx = c*x + ic          (independent of y)
//   sy = id_*x + ie*y + if_
// Only 2 transcendentals + 1 rcp per thread (~50 VALU ops total).
__global__ __launch_bounds__(256) void TCR_52536039964687_warp(
    const float* __restrict__ img,
    const float* __restrict__ rnd,
    float* __restrict__ out) {
    // XCD-affinity swizzle: all 256 rows of image b land on XCD b%8
    // (assumes HW round-robin xcd = bid % 8; perf-only assumption).
    int w = blockIdx.x;             // [0, 64*256)
    int xcd = w & (NXCD - 1);
    int t = w >> 3;                 // within-XCD sequence [0, 2048)
    int b = ((t >> 8) << 3) | xcd;  // image index
    int y = t & 255;                // output row
    int x = threadIdx.x;            // output col

    // ---- per-image inverse affine coefficients (simplified) ----
    const float r = rnd[b];
    const float ANG  = 0.34906585039886590f;   // deg2rad(20)
    const float ANG2 = 0.69813170079773179f;   // 2*ANG
    const float Wc = (float)IMH;    // reference: Wc = img.shape[2]
    const float Hc = (float)IMW;    // reference: Hc = img.shape[3]

    float tx  = 12.0f * r - 6.0f;
    float ty  = tx;
    float rho = ANG2 * r - ANG;     // rotation == shear-x == shear-y

    float s = __sinf(rho);
    float c = __cosf(rho);
    float cb = 2.f * c * c - 1.f;   // cos(2*rho)
    float sb = 2.f * s * c;         // sin(2*rho)
    float rcb = 1.f / cb;           // |2*rho| <= 0.7 rad -> cb >= 0.766

    float ia  = c;
    float ic  = 0.5f * Wc * (1.f - c) - tx;
    float id_ = -sb * c * rcb;
    float ie  = c * rcb;
    float P   = 0.5f * (Wc * c - Wc + 2.f * tx);
    float Q   = 0.5f * (Hc * c - Wc * cb + 2.f * ty * cb - Wc * sb + 2.f * tx * sb);
    float if_ = (sb * P - Q) * rcb;

    // ---- source position ----
    float fx = (float)x, fy = (float)y;
    float sx = ia * fx + ic;
    float sy = id_ * fx + ie * fy + if_;

    float x0f = floorf(sx), y0f = floorf(sy);
    int x0 = (int)x0f, y0 = (int)y0f;
    float wx = sx - x0f, wy = sy - y0f;

    // ---- fused x-taps: one 8B load at lx covers x0 and x0+1 ----
    int lx = min(max(x0, 0), IMW - 2);
    float wl = (x0 == lx) ? (1.f - wx) : ((x0 == lx - 1) ? wx : 0.f);
    float wh = (x0 == lx) ? wx : ((x0 == lx + 1) ? (1.f - wx) : 0.f);

    // ---- y-taps: validity folded into row weights ----
    int y1 = y0 + 1;
    float wy0 = ((y0 >= 0) & (y0 < IMH)) ? (1.f - wy) : 0.f;
    float wy1 = ((y1 >= 0) & (y1 < IMH)) ? wy : 0.f;
    int cy0 = min(max(y0, 0), IMH - 1);
    int cy1 = min(max(y1, 0), IMH - 1);

    const float* base = img + (size_t)b * CH * HW;
    const float* r0 = base + cy0 * IMW + lx;
    const float* r1 = base + cy1 * IMW + lx;
    float* ob = out + (size_t)b * CH * HW + y * IMW + x;

    #pragma unroll
    for (int ch = 0; ch < CH; ++ch) {
        F2 a0 = load_f2(r0 + ch * HW);
        F2 a1 = load_f2(r1 + ch * HW);
        float v = (a0.lo * wl + a0.hi * wh) * wy0
                + (a1.lo * wl + a1.hi * wh) * wy1;
        // output is never re-read: nontemporal store keeps L2 for input
        __builtin_nontemporal_store(v, ob + ch * HW);
    }
}

extern "C" void kernel_launch(void* const* d_in, const int* in_sizes, int n_in,
                              void* d_out, int out_size, void* d_ws, size_t ws_size,
                              hipStream_t stream) {
    const float* img = (const float*)d_in[0];
    const float* rnd = (const float*)d_in[1];
    float* out = (float*)d_out;
    (void)d_ws; (void)ws_size;

    hipLaunchKernelGGL(TCR_52536039964687_warp, dim3(BATCH * IMH), dim3(256), 0, stream,
                       img, rnd, out);
}

// Round 5
// 26.073 us; speedup vs baseline: 2.6733x; 1.4068x over previous
//
#include <hip/hip_runtime.h>
#include <math.h>

// B=64, C=3, H=W=256 fixed by the reference problem.
#define BATCH 64
#define CH 3
#define IMH 256
#define IMW 256
#define HW (IMH * IMW)
#define NXCD 8

// LDS tile: staged source window per 64x64 output tile, one channel at a time.
// Row span bound: (|id_|max + ie_max)*63 + 2 = (0.7915+1.2267)*63+2 < 130.
#define NRMAX 132
#define XW 68          // staged cols (bound: 63*c+1 taps + <=3 align slack + 1)
#define XW4 (XW / 4)   // float4 per staged row

__device__ __forceinline__ int clampi(int v, int lo, int hi) {
    return min(max(v, lo), hi);
}

__global__ __launch_bounds__(256, 4) void TCR_52536039964687_warp(
    const float* __restrict__ img,
    const float* __restrict__ rnd,
    float* __restrict__ out) {
    __shared__ float lds[NRMAX * XW];

    // 1024 blocks = 64 images x 16 tiles (4x4 of 64x64).
    // XCD-affinity swizzle: all 16 tiles of image b land on XCD b%8
    // (assumes HW round-robin xcd = bid % 8; perf-only assumption).
    int w = blockIdx.x;
    int xcd = w & (NXCD - 1);
    int t = w >> 3;                  // 0..127 within XCD
    int b = ((t >> 4) << 3) | xcd;   // image index
    int tile = t & 15;
    int X0 = (tile & 3) << 6;        // tile col origin
    int Y0 = (tile >> 2) << 6;       // tile row origin

    int tid = threadIdx.x;
    int dx = tid & 63;               // output col within tile
    int qy = tid >> 6;               // 0..3: thread's row phase

    // ---- per-image inverse affine coefficients (simplified; a==0 exactly) ----
    const float r = rnd[b];
    const float ANG  = 0.34906585039886590f;   // deg2rad(20)
    const float ANG2 = 0.69813170079773179f;   // 2*ANG
    const float Wc = (float)IMH;
    const float Hc = (float)IMW;

    float tx  = 12.0f * r - 6.0f;
    float ty  = tx;
    float rho = ANG2 * r - ANG;

    float s = __sinf(rho);
    float c = __cosf(rho);            // c >= 0.9397 > 0
    float cb = 2.f * c * c - 1.f;     // cos(2*rho) >= 0.766
    float sb = 2.f * s * c;           // sin(2*rho)
    float rcb = 1.f / cb;

    float ic  = 0.5f * Wc * (1.f - c) - tx;
    float id_ = -sb * c * rcb;        // |id_| <= 0.7915
    float ie  = c * rcb;              // 1.0 <= ie <= 1.2267
    float P   = 0.5f * (Wc * c - Wc + 2.f * tx);
    float Q   = 0.5f * (Hc * c - Wc * cb + 2.f * ty * cb - Wc * sb + 2.f * tx * sb);
    float if_ = (sb * P - Q) * rcb;
    // sx = fmaf(c, x, ic)                    (independent of y)
    // sy = fmaf(id_, x, fmaf(ie, y, if_))

    // ---- tile source bounds via the 4 corners ----
    // Same fmaf composition as per-output below; fma/add/mul are monotone per
    // operand, ie>0, c>0 -> corner min/max bound every (x,y) in the tile.
    float X0f = (float)X0, X1f = (float)(X0 + 63);
    float Y0f = (float)Y0, Y1f = (float)(Y0 + 63);
    float sxlo = fmaf(c, X0f, ic);            // c>0 -> min over tile
    int lxmin = clampi((int)floorf(sxlo), 0, IMW - 2);
    int axlo = lxmin & ~3;                    // 16B-aligned staging origin

    float g0 = fmaf(ie, Y0f, if_);
    float g1 = fmaf(ie, Y1f, if_);            // g1 >= g0
    float syA = fmaf(id_, X0f, g0), syB = fmaf(id_, X1f, g0);
    float syC = fmaf(id_, X0f, g1), syD = fmaf(id_, X1f, g1);
    float symin = fminf(fminf(syA, syB), fminf(syC, syD));
    float symax = fmaxf(fmaxf(syA, syB), fmaxf(syC, syD));
    int rlo = clampi((int)floorf(symin), 0, IMH - 1);
    int rhi = clampi((int)floorf(symax) + 1, 0, IMH - 1);
    int NR = rhi - rlo + 1;                   // <= 130 by construction

    // ---- per-thread x taps (channel- and row-invariant) ----
    float fx = (float)(X0 + dx);
    float sx = fmaf(c, fx, ic);
    float x0f = floorf(sx);
    int x0 = (int)x0f;
    float wx = sx - x0f;
    int lx = clampi(x0, 0, IMW - 2);          // >= lxmin >= axlo (monotone clamp)
    float wl = (x0 == lx) ? (1.f - wx) : ((x0 == lx - 1) ? wx : 0.f);
    float wh = (x0 == lx) ? wx : ((x0 == lx + 1) ? (1.f - wx) : 0.f);
    int px = lx - axlo;                       // 0..66

    // ---- per-thread y taps: 16 rows (Y0+qy+4k), precomputed, reused per ch ----
    int   a0[16], a1[16];
    float wy0[16], wy1[16];
    #pragma unroll
    for (int k = 0; k < 16; ++k) {
        float fy = (float)(Y0 + qy + 4 * k);
        float sy = fmaf(id_, fx, fmaf(ie, fy, if_));
        float y0f = floorf(sy);
        int y0 = (int)y0f;
        int y1 = y0 + 1;
        float wy = sy - y0f;
        wy0[k] = ((y0 >= 0) & (y0 < IMH)) ? (1.f - wy) : 0.f;
        wy1[k] = ((y1 >= 0) & (y1 < IMH)) ? wy : 0.f;
        // clamp is monotone -> staged window [rlo,rhi] contains both rows
        a0[k] = (clampi(y0, 0, IMH - 1) - rlo) * XW + px;
        a1[k] = (clampi(y1, 0, IMH - 1) - rlo) * XW + px;
    }

    const float* ibase = img + (size_t)b * CH * HW;
    float* obase = out + (size_t)b * CH * HW + (Y0 + qy) * IMW + X0 + dx;
    int nq = NR * XW4;                        // float4 count to stage

    for (int ch = 0; ch < CH; ++ch) {
        const float* cbase = ibase + ch * HW;
        // ---- stage: coalesced float4, every needed line touched once ----
        for (int e = tid; e < nq; e += 256) {
            unsigned ue = (unsigned)e;
            unsigned row = ue / XW4;          // magic-mul
            unsigned q = ue - row * XW4;
            int gq = min(axlo + 4 * (int)q, IMW - 4);  // stay inside the row
            float4 v = *(const float4*)(cbase + (rlo + (int)row) * IMW + gq);
            *((float4*)&lds[row * XW + 4 * q]) = v;    // (68*row+4q)%4==0 -> b128
        }
        __syncthreads();
        // ---- sample from LDS ----
        #pragma unroll
        for (int k = 0; k < 16; ++k) {
            float l00 = lds[a0[k]], l01 = lds[a0[k] + 1];
            float l10 = lds[a1[k]], l11 = lds[a1[k] + 1];
            float v = (l00 * wl + l01 * wh) * wy0[k]
                    + (l10 * wl + l11 * wh) * wy1[k];
            __builtin_nontemporal_store(v, obase + ch * HW + 4 * k * IMW);
        }
        __syncthreads();
    }
}

extern "C" void kernel_launch(void* const* d_in, const int* in_sizes, int n_in,
                              void* d_out, int out_size, void* d_ws, size_t ws_size,
                              hipStream_t stream) {
    const float* img = (const float*)d_in[0];
    const float* rnd = (const float*)d_in[1];
    float* out = (float*)d_out;
    (void)d_ws; (void)ws_size;

    hipLaunchKernelGGL(TCR_52536039964687_warp, dim3(BATCH * 16), dim3(256), 0, stream,
                       img, rnd, out);
}